// Round 4
// baseline (199.508 us; speedup 1.0000x reference)
//
#include <hip/hip_runtime.h>
#include <hip/hip_bf16.h>
#include <cstddef>

// Problem constants (from reference setup_inputs)
#define BB 16
#define CC 192
#define HH 64
#define WW 64
#define LL 4096   // H*W
#define DTR 12    // dt_rank
#define KK 14     // dt_rank + 2*d_state, d_state = 1

__device__ __forceinline__ float silu_f(float v) {
  return v / (1.f + __expf(-v));
}

// ---------------------------------------------------------------------------
// K1: depthwise 5x5 conv (SAME, zero pad) + bias + SiLU — LDS-free.
// One wave (64 threads) per (b,c) plane; lane = x column. Stream rows
// top->bottom: per input row, 1 coalesced load + 4 shuffles give the 5
// horizontal taps; each row contributes its 5 kernel-row dots into a ring of
// 5 output-row accumulators (static indices under unroll-5). No LDS at all.
// ---------------------------------------------------------------------------
__global__ __launch_bounds__(64) void conv_silu_kernel(
    const float* __restrict__ x, const float* __restrict__ cw,
    const float* __restrict__ cb, float* __restrict__ xs) {
  const int bc = blockIdx.x;           // b*CC + c
  const int c = bc % CC;
  const int lane = threadIdx.x;        // x column 0..63

  float w[25];
#pragma unroll
  for (int k = 0; k < 25; ++k) w[k] = cw[c * 25 + k];
  const float bias = cb[c];

  const float* xp = x + (size_t)bc * LL + lane;
  float* op = xs + (size_t)bc * LL + lane;

  float acc[5];
#pragma unroll
  for (int i = 0; i < 5; ++i) acc[i] = 0.f;

  // out[y] = sum_ky w[ky]·row[y+ky-2]; input row r feeds outputs y=r-ky+2.
  // Output row yf = r-2 completes at the end of iteration r.
#pragma unroll 5
  for (int r = 0; r < 70; ++r) {
    float v = 0.f;
    if (r < 64) v = xp[r * 64];
    float vm2 = __shfl_up(v, 2u, 64);
    float vm1 = __shfl_up(v, 1u, 64);
    float vp1 = __shfl_down(v, 1u, 64);
    float vp2 = __shfl_down(v, 2u, 64);
    if (lane < 2) vm2 = 0.f;
    if (lane < 1) vm1 = 0.f;
    if (lane > 62) vp1 = 0.f;
    if (lane > 61) vp2 = 0.f;
    float t[5] = {vm2, vm1, v, vp1, vp2};
#pragma unroll
    for (int ky = 0; ky < 5; ++ky) {
      const int y = r - ky + 2;          // output row receiving this row w/ ky
      if (y >= 0 && y < 64) {
        float s = acc[y % 5];            // static index under unroll-5
#pragma unroll
        for (int kx = 0; kx < 5; ++kx) s += w[ky * 5 + kx] * t[kx];
        acc[y % 5] = s;
      }
    }
    const int yf = r - 2;
    if (yf >= 0 && yf < 64) {
      float a = acc[yf % 5] + bias;
      op[yf * 64] = silu_f(a);
      acc[yf % 5] = 0.f;
    }
  }
}

// ---------------------------------------------------------------------------
// K2: x_dbl[b][k][l] = sum_c x_proj_w[k][c] * xs[b][c][l]   (k = 0..13)
// block = (256-l strip, b); 4 waves x 48 channels; lane owns 4 l's (float4).
// ---------------------------------------------------------------------------
__global__ __launch_bounds__(256) void proj_kernel(
    const float* __restrict__ xs, const float* __restrict__ xpw,
    float* __restrict__ xdbl) {
  const int b = blockIdx.y;
  const int l0 = blockIdx.x * 256;
  const int tid = threadIdx.x;
  const int lane = tid & 63;
  const int g = tid >> 6;  // wave id, 0..3

  __shared__ float part[4][KK][256];

  float4 acc[KK];
#pragma unroll
  for (int k = 0; k < KK; ++k) acc[k] = make_float4(0.f, 0.f, 0.f, 0.f);

  const float* bp = xs + ((size_t)(b * CC + g * 48)) * LL + l0 + lane * 4;
#pragma unroll 4
  for (int cc = 0; cc < 48; ++cc) {
    float4 v = *(const float4*)(bp + (size_t)cc * LL);
    const int c = g * 48 + cc;
#pragma unroll
    for (int k = 0; k < KK; ++k) {
      float wv = xpw[k * CC + c];
      acc[k].x += wv * v.x;
      acc[k].y += wv * v.y;
      acc[k].z += wv * v.z;
      acc[k].w += wv * v.w;
    }
  }
#pragma unroll
  for (int k = 0; k < KK; ++k)
    *(float4*)&part[g][k][lane * 4] = acc[k];
  __syncthreads();

  for (int idx = tid; idx < KK * 256; idx += 256) {
    int k = idx >> 8, ln = idx & 255;
    float v = part[0][k][ln] + part[1][k][ln] + part[2][k][ln] + part[3][k][ln];
    xdbl[((size_t)b * KK + k) * LL + l0 + ln] = v;
  }
}

// ---------------------------------------------------------------------------
// K3: fused dt-projection + softplus + selective scan + output.
// One wave per (b,c) sequence; 16 chunks of 256 l's; lane owns 4 contiguous
// l's per chunk (float4, lane-contiguous). Shfl scan + shfl(63) carry.
// ---------------------------------------------------------------------------
__global__ __launch_bounds__(64) void scan_kernel(
    const float* __restrict__ xs, const float* __restrict__ xdbl,
    const float* __restrict__ dtw, const float* __restrict__ dtb,
    const float* __restrict__ A_logs, const float* __restrict__ Ds,
    float* __restrict__ y) {
  const int bc = blockIdx.x;
  const int b = bc / CC;
  const int c = bc - b * CC;
  const int lane = threadIdx.x;

  const float Ac = -__expf(A_logs[c]);  // d_state = 1
  const float Dc = Ds[c];
  float dw[DTR];
#pragma unroll
  for (int r = 0; r < DTR; ++r) dw[r] = dtw[c * DTR + r];
  const float db = dtb[c];

  const float* xp = xs + (size_t)bc * LL;
  const float* xb = xdbl + (size_t)b * KK * LL;
  float* yp = y + (size_t)bc * LL;

  float hcarry = 0.f;

  for (int sc = 0; sc < 16; ++sc) {
    const int base = sc * 256 + lane * 4;

    float4 x4 = *(const float4*)(xp + base);
    float4 B4 = *(const float4*)(xb + 12 * LL + base);
    float4 C4 = *(const float4*)(xb + 13 * LL + base);
    float4 dr[DTR];
#pragma unroll
    for (int r = 0; r < DTR; ++r)
      dr[r] = *(const float4*)(xb + r * LL + base);

    float xx[4] = {x4.x, x4.y, x4.z, x4.w};
    float bb[4] = {B4.x, B4.y, B4.z, B4.w};
    float av[4], bv[4];
    float aggA = 1.f, aggB = 0.f;
#pragma unroll
    for (int q = 0; q < 4; ++q) {
      float z = db;
#pragma unroll
      for (int r = 0; r < DTR; ++r) z += dw[r] * ((&dr[r].x)[q]);
      float delta = (z > 15.f) ? z : __logf(1.f + __expf(z));
      float a = __expf(delta * Ac);
      float be = delta * bb[q] * xx[q];
      av[q] = a;
      bv[q] = be;
      aggA = a * aggA;
      aggB = a * aggB + be;
    }

    float incA = aggA, incB = aggB;
#pragma unroll
    for (int s = 1; s < 64; s <<= 1) {
      float pA = __shfl_up(incA, (unsigned)s, 64);
      float pB = __shfl_up(incB, (unsigned)s, 64);
      if (lane >= s) {
        incB = incA * pB + incB;
        incA = incA * pA;
      }
    }
    float eA = __shfl_up(incA, 1u, 64);
    float eB = __shfl_up(incB, 1u, 64);
    if (lane == 0) { eA = 1.f; eB = 0.f; }
    float tA = __shfl(incA, 63, 64);
    float tB = __shfl(incB, 63, 64);

    float h = eA * hcarry + eB;
    float ov[4];
#pragma unroll
    for (int q = 0; q < 4; ++q) {
      h = av[q] * h + bv[q];
      ov[q] = h * ((&C4.x)[q]) + xx[q] * Dc;
    }
    float4 o;
    o.x = ov[0]; o.y = ov[1]; o.z = ov[2]; o.w = ov[3];
    *(float4*)(yp + base) = o;

    hcarry = tA * hcarry + tB;
  }
}

// ---------------------------------------------------------------------------
extern "C" void kernel_launch(void* const* d_in, const int* in_sizes, int n_in,
                              void* d_out, int out_size, void* d_ws,
                              size_t ws_size, hipStream_t stream) {
  const float* x        = (const float*)d_in[0];
  const float* conv_w   = (const float*)d_in[1];
  const float* conv_b   = (const float*)d_in[2];
  const float* x_proj_w = (const float*)d_in[3];
  const float* dt_w     = (const float*)d_in[4];
  const float* dt_b     = (const float*)d_in[5];
  const float* A_logs   = (const float*)d_in[6];
  const float* Ds       = (const float*)d_in[7];
  float* out = (float*)d_out;

  char* ws = (char*)d_ws;
  const size_t plane_bytes = (size_t)BB * CC * LL * sizeof(float);  // 50 MB
  float* xs   = (float*)ws;
  float* xdbl = (float*)(ws + plane_bytes);  // BB*KK*LL floats = 3.67 MB

  conv_silu_kernel<<<dim3(BB * CC), 64, 0, stream>>>(x, conv_w, conv_b, xs);
  proj_kernel<<<dim3(LL / 256, BB), 256, 0, stream>>>(xs, x_proj_w, xdbl);
  scan_kernel<<<dim3(BB * CC), 64, 0, stream>>>(xs, xdbl, dt_w, dt_b,
                                                A_logs, Ds, out);
}

// Round 5
// 187.717 us; speedup vs baseline: 1.0628x; 1.0628x over previous
//
#include <hip/hip_runtime.h>
#include <hip/hip_bf16.h>
#include <cstddef>

// Problem constants (from reference setup_inputs)
#define BB 16
#define CC 192
#define HH 64
#define WW 64
#define LL 4096   // H*W
#define DTR 12    // dt_rank
#define KK 14     // dt_rank + 2*d_state, d_state = 1

__device__ __forceinline__ float silu_f(float v) {
  return v / (1.f + __expf(-v));
}

// ---------------------------------------------------------------------------
// K1: depthwise 5x5 conv (SAME, zero pad) + bias + SiLU — LDS-free.
// One block (4 waves) per (b,c) plane; wave w owns output rows 16w..16w+15.
// Lane = x column. Each wave streams 20 input rows (2-row halo each side):
// 1 coalesced load + 4 shuffles per row; ring of 5 output-row accumulators
// with STATIC indices (conditions depend only on unrolled r,ky).
// ---------------------------------------------------------------------------
__global__ __launch_bounds__(256) void conv_silu_kernel(
    const float* __restrict__ x, const float* __restrict__ cw,
    const float* __restrict__ cb, float* __restrict__ xs) {
  const int bc = blockIdx.x;           // b*CC + c
  const int c = bc % CC;
  const int tid = threadIdx.x;
  const int lane = tid & 63;           // x column 0..63
  const int wv = tid >> 6;             // wave 0..3
  const int oy0 = wv * 16;             // first output row of this wave

  float w[25];
#pragma unroll
  for (int k = 0; k < 25; ++k) w[k] = cw[c * 25 + k];
  const float bias = cb[c];

  const float* xp = x + (size_t)bc * LL + lane;
  float* op = xs + (size_t)bc * LL + lane;

  float acc[5];
#pragma unroll
  for (int i = 0; i < 5; ++i) acc[i] = 0.f;

  // input row gr = oy0 + r - 2; output row y = gr - ky + 2 = oy0 + (r - ky).
  // y in-wave iff 0 <= r-ky < 16 (static!). Row oy0+r-4 completes at iter r.
#pragma unroll 5
  for (int r = 0; r < 20; ++r) {
    const int gr = oy0 + r - 2;
    float v = 0.f;
    if ((unsigned)gr < 64u) v = xp[gr * 64];
    float vm2 = __shfl_up(v, 2u, 64);
    float vm1 = __shfl_up(v, 1u, 64);
    float vp1 = __shfl_down(v, 1u, 64);
    float vp2 = __shfl_down(v, 2u, 64);
    if (lane < 2) vm2 = 0.f;
    if (lane < 1) vm1 = 0.f;
    if (lane > 62) vp1 = 0.f;
    if (lane > 61) vp2 = 0.f;
    float t[5] = {vm2, vm1, v, vp1, vp2};
#pragma unroll
    for (int ky = 0; ky < 5; ++ky) {
      if (r >= ky && (r - ky) < 16) {        // static under unroll
        float s = acc[(r - ky) % 5];
#pragma unroll
        for (int kx = 0; kx < 5; ++kx) s += w[ky * 5 + kx] * t[kx];
        acc[(r - ky) % 5] = s;
      }
    }
    if (r >= 4) {                            // static under unroll
      const int yf = oy0 + r - 4;
      float a = acc[(r - 4) % 5] + bias;
      op[yf * 64] = silu_f(a);
      acc[(r - 4) % 5] = 0.f;
    }
  }
}

// ---------------------------------------------------------------------------
// K2: x_dbl[b][k][l] = sum_c x_proj_w[k][c] * xs[b][c][l]   (k = 0..13)
// block = (128-l strip, b), 512 threads = 8 waves x 24 channels; lane owns
// 2 l's (float2, lane-contiguous). Padded LDS partials, one reduce.
// ---------------------------------------------------------------------------
__global__ __launch_bounds__(512) void proj_kernel(
    const float* __restrict__ xs, const float* __restrict__ xpw,
    float* __restrict__ xdbl) {
  const int b = blockIdx.y;
  const int l0 = blockIdx.x * 128;
  const int tid = threadIdx.x;
  const int lane = tid & 63;
  const int g = tid >> 6;  // wave id, 0..7

  __shared__ float part[8][KK][132];   // pad 128->132 to break p-stride

  float2 acc[KK];
#pragma unroll
  for (int k = 0; k < KK; ++k) acc[k] = make_float2(0.f, 0.f);

  const float* bp = xs + ((size_t)(b * CC + g * 24)) * LL + l0 + lane * 2;
#pragma unroll 4
  for (int cc = 0; cc < 24; ++cc) {
    float2 v = *(const float2*)(bp + (size_t)cc * LL);
    const int c = g * 24 + cc;
#pragma unroll
    for (int k = 0; k < KK; ++k) {
      float wv = xpw[k * CC + c];
      acc[k].x += wv * v.x;
      acc[k].y += wv * v.y;
    }
  }
#pragma unroll
  for (int k = 0; k < KK; ++k)
    *(float2*)&part[g][k][lane * 2] = acc[k];
  __syncthreads();

  // reduce 8 wave-partials, write out (KK*128 = 1792 values)
  for (int idx = tid; idx < KK * 128; idx += 512) {
    int k = idx >> 7, ln = idx & 127;
    float v = 0.f;
#pragma unroll
    for (int p = 0; p < 8; ++p) v += part[p][k][ln];
    xdbl[((size_t)b * KK + k) * LL + l0 + ln] = v;
  }
}

// ---------------------------------------------------------------------------
// K3: fused dt-projection + softplus + selective scan + output.
// One wave per (b,c) sequence; 16 chunks of 256 l's; lane owns 4 contiguous
// l's per chunk (float4, lane-contiguous). Shfl scan + shfl(63) carry.
// ---------------------------------------------------------------------------
__global__ __launch_bounds__(64) void scan_kernel(
    const float* __restrict__ xs, const float* __restrict__ xdbl,
    const float* __restrict__ dtw, const float* __restrict__ dtb,
    const float* __restrict__ A_logs, const float* __restrict__ Ds,
    float* __restrict__ y) {
  const int bc = blockIdx.x;
  const int b = bc / CC;
  const int c = bc - b * CC;
  const int lane = threadIdx.x;

  const float Ac = -__expf(A_logs[c]);  // d_state = 1
  const float Dc = Ds[c];
  float dw[DTR];
#pragma unroll
  for (int r = 0; r < DTR; ++r) dw[r] = dtw[c * DTR + r];
  const float db = dtb[c];

  const float* xp = xs + (size_t)bc * LL;
  const float* xb = xdbl + (size_t)b * KK * LL;
  float* yp = y + (size_t)bc * LL;

  float hcarry = 0.f;

  for (int sc = 0; sc < 16; ++sc) {
    const int base = sc * 256 + lane * 4;

    float4 x4 = *(const float4*)(xp + base);
    float4 B4 = *(const float4*)(xb + 12 * LL + base);
    float4 C4 = *(const float4*)(xb + 13 * LL + base);
    float4 dr[DTR];
#pragma unroll
    for (int r = 0; r < DTR; ++r)
      dr[r] = *(const float4*)(xb + r * LL + base);

    float xx[4] = {x4.x, x4.y, x4.z, x4.w};
    float bb[4] = {B4.x, B4.y, B4.z, B4.w};
    float av[4], bv[4];
    float aggA = 1.f, aggB = 0.f;
#pragma unroll
    for (int q = 0; q < 4; ++q) {
      float z = db;
#pragma unroll
      for (int r = 0; r < DTR; ++r) z += dw[r] * ((&dr[r].x)[q]);
      float delta = (z > 15.f) ? z : __logf(1.f + __expf(z));
      float a = __expf(delta * Ac);
      float be = delta * bb[q] * xx[q];
      av[q] = a;
      bv[q] = be;
      aggA = a * aggA;
      aggB = a * aggB + be;
    }

    float incA = aggA, incB = aggB;
#pragma unroll
    for (int s = 1; s < 64; s <<= 1) {
      float pA = __shfl_up(incA, (unsigned)s, 64);
      float pB = __shfl_up(incB, (unsigned)s, 64);
      if (lane >= s) {
        incB = incA * pB + incB;
        incA = incA * pA;
      }
    }
    float eA = __shfl_up(incA, 1u, 64);
    float eB = __shfl_up(incB, 1u, 64);
    if (lane == 0) { eA = 1.f; eB = 0.f; }
    float tA = __shfl(incA, 63, 64);
    float tB = __shfl(incB, 63, 64);

    float h = eA * hcarry + eB;
    float ov[4];
#pragma unroll
    for (int q = 0; q < 4; ++q) {
      h = av[q] * h + bv[q];
      ov[q] = h * ((&C4.x)[q]) + xx[q] * Dc;
    }
    float4 o;
    o.x = ov[0]; o.y = ov[1]; o.z = ov[2]; o.w = ov[3];
    *(float4*)(yp + base) = o;

    hcarry = tA * hcarry + tB;
  }
}

// ---------------------------------------------------------------------------
extern "C" void kernel_launch(void* const* d_in, const int* in_sizes, int n_in,
                              void* d_out, int out_size, void* d_ws,
                              size_t ws_size, hipStream_t stream) {
  const float* x        = (const float*)d_in[0];
  const float* conv_w   = (const float*)d_in[1];
  const float* conv_b   = (const float*)d_in[2];
  const float* x_proj_w = (const float*)d_in[3];
  const float* dt_w     = (const float*)d_in[4];
  const float* dt_b     = (const float*)d_in[5];
  const float* A_logs   = (const float*)d_in[6];
  const float* Ds       = (const float*)d_in[7];
  float* out = (float*)d_out;

  char* ws = (char*)d_ws;
  const size_t plane_bytes = (size_t)BB * CC * LL * sizeof(float);  // 50 MB
  float* xs   = (float*)ws;
  float* xdbl = (float*)(ws + plane_bytes);  // BB*KK*LL floats = 3.67 MB

  conv_silu_kernel<<<dim3(BB * CC), 256, 0, stream>>>(x, conv_w, conv_b, xs);
  proj_kernel<<<dim3(LL / 128, BB), 512, 0, stream>>>(xs, x_proj_w, xdbl);
  scan_kernel<<<dim3(BB * CC), 64, 0, stream>>>(xs, xdbl, dt_w, dt_b,
                                                A_logs, Ds, out);
}

// Round 6
// 171.884 us; speedup vs baseline: 1.1607x; 1.0921x over previous
//
#include <hip/hip_runtime.h>
#include <hip/hip_bf16.h>
#include <cstddef>

// Problem constants (from reference setup_inputs)
#define BB 16
#define CC 192
#define HH 64
#define WW 64
#define LL 4096   // H*W
#define DTR 12    // dt_rank
#define KK 14     // dt_rank + 2*d_state, d_state = 1

__device__ __forceinline__ float silu_f(float v) {
  return v / (1.f + __expf(-v));
}

// ---------------------------------------------------------------------------
// K1: depthwise 5x5 conv (SAME, zero pad) + bias + SiLU — LDS-free.
// One block (4 waves) per (b,c) plane; wave w owns output rows 16w..16w+15.
// Lane = x column. PRELOAD all 20 input rows (2-row halo each side) into
// registers (20 loads in flight), then: 4 shuffles per row + ring of 5
// output-row accumulators with static indices.
// ---------------------------------------------------------------------------
__global__ __launch_bounds__(256) void conv_silu_kernel(
    const float* __restrict__ x, const float* __restrict__ cw,
    const float* __restrict__ cb, float* __restrict__ xs) {
  const int bc = blockIdx.x;           // b*CC + c
  const int c = bc % CC;
  const int tid = threadIdx.x;
  const int lane = tid & 63;           // x column 0..63
  const int wv = tid >> 6;             // wave 0..3
  const int oy0 = wv * 16;             // first output row of this wave

  float w[25];
#pragma unroll
  for (int k = 0; k < 25; ++k) w[k] = cw[c * 25 + k];
  const float bias = cb[c];

  const float* xp = x + (size_t)bc * LL + lane;
  float* op = xs + (size_t)bc * LL + lane;

  // preload 20 rows (wave-uniform predication; all loads issue up front)
  float rv[20];
#pragma unroll
  for (int r = 0; r < 20; ++r) {
    const int gr = oy0 + r - 2;
    float v = 0.f;
    if ((unsigned)gr < 64u) v = xp[gr * 64];
    rv[r] = v;
  }

  float acc[5];
#pragma unroll
  for (int i = 0; i < 5; ++i) acc[i] = 0.f;

  // input row gr = oy0 + r - 2; output row y = oy0 + (r - ky).
  // y in-wave iff 0 <= r-ky < 16 (static). Row oy0+r-4 completes at iter r.
#pragma unroll
  for (int r = 0; r < 20; ++r) {
    float v = rv[r];
    float vm2 = __shfl_up(v, 2u, 64);
    float vm1 = __shfl_up(v, 1u, 64);
    float vp1 = __shfl_down(v, 1u, 64);
    float vp2 = __shfl_down(v, 2u, 64);
    if (lane < 2) vm2 = 0.f;
    if (lane < 1) vm1 = 0.f;
    if (lane > 62) vp1 = 0.f;
    if (lane > 61) vp2 = 0.f;
    float t[5] = {vm2, vm1, v, vp1, vp2};
#pragma unroll
    for (int ky = 0; ky < 5; ++ky) {
      if (r >= ky && (r - ky) < 16) {        // static under unroll
        float s = acc[(r - ky) % 5];
#pragma unroll
        for (int kx = 0; kx < 5; ++kx) s += w[ky * 5 + kx] * t[kx];
        acc[(r - ky) % 5] = s;
      }
    }
    if (r >= 4) {                            // static under unroll
      const int yf = oy0 + r - 4;
      float a = acc[(r - 4) % 5] + bias;
      op[yf * 64] = silu_f(a);
      acc[(r - 4) % 5] = 0.f;
    }
  }
}

// ---------------------------------------------------------------------------
// K2: x_dbl[b][k][l] = sum_c x_proj_w[k][c] * xs[b][c][l]   (k = 0..13)
// block = (128-l strip, b), 512 threads = 8 waves x 24 channels; lane owns
// 2 l's (float2, lane-contiguous). Padded LDS partials, one reduce.
// ---------------------------------------------------------------------------
__global__ __launch_bounds__(512) void proj_kernel(
    const float* __restrict__ xs, const float* __restrict__ xpw,
    float* __restrict__ xdbl) {
  const int b = blockIdx.y;
  const int l0 = blockIdx.x * 128;
  const int tid = threadIdx.x;
  const int lane = tid & 63;
  const int g = tid >> 6;  // wave id, 0..7

  __shared__ float part[8][KK][132];   // pad 128->132 to break p-stride

  float2 acc[KK];
#pragma unroll
  for (int k = 0; k < KK; ++k) acc[k] = make_float2(0.f, 0.f);

  const float* bp = xs + ((size_t)(b * CC + g * 24)) * LL + l0 + lane * 2;
#pragma unroll 4
  for (int cc = 0; cc < 24; ++cc) {
    float2 v = *(const float2*)(bp + (size_t)cc * LL);
    const int c = g * 24 + cc;
#pragma unroll
    for (int k = 0; k < KK; ++k) {
      float wv = xpw[k * CC + c];
      acc[k].x += wv * v.x;
      acc[k].y += wv * v.y;
    }
  }
#pragma unroll
  for (int k = 0; k < KK; ++k)
    *(float2*)&part[g][k][lane * 2] = acc[k];
  __syncthreads();

  for (int idx = tid; idx < KK * 128; idx += 512) {
    int k = idx >> 7, ln = idx & 127;
    float v = 0.f;
#pragma unroll
    for (int p = 0; p < 8; ++p) v += part[p][k][ln];
    xdbl[((size_t)b * KK + k) * LL + l0 + ln] = v;
  }
}

// ---------------------------------------------------------------------------
// K3: fused dt-projection + softplus + selective scan + output.
// One wave per (b,c) sequence; 16 chunks of 256 l's; lane owns 4 contiguous
// l's per chunk. SOFTWARE-PIPELINED: double register buffer, chunk sc+1's
// 15 float4 loads are in flight while chunk sc is scanned.
// ---------------------------------------------------------------------------
__global__ __launch_bounds__(64) void scan_kernel(
    const float* __restrict__ xs, const float* __restrict__ xdbl,
    const float* __restrict__ dtw, const float* __restrict__ dtb,
    const float* __restrict__ A_logs, const float* __restrict__ Ds,
    float* __restrict__ y) {
  const int bc = blockIdx.x;
  const int b = bc / CC;
  const int c = bc - b * CC;
  const int lane = threadIdx.x;

  const float Ac = -__expf(A_logs[c]);  // d_state = 1
  const float Dc = Ds[c];
  float dw[DTR];
#pragma unroll
  for (int r = 0; r < DTR; ++r) dw[r] = dtw[c * DTR + r];
  const float db = dtb[c];

  const float* xp = xs + (size_t)bc * LL;
  const float* xb = xdbl + (size_t)b * KK * LL;
  float* yp = y + (size_t)bc * LL;

  float hcarry = 0.f;

  // buf layout: [0]=x4, [1]=B4, [2]=C4, [3..14]=dr[0..11]
  auto load_chunk = [&](int sc, float4* dst) {
    const int base = sc * 256 + lane * 4;
    dst[0] = *(const float4*)(xp + base);
    dst[1] = *(const float4*)(xb + 12 * LL + base);
    dst[2] = *(const float4*)(xb + 13 * LL + base);
#pragma unroll
    for (int r = 0; r < DTR; ++r)
      dst[3 + r] = *(const float4*)(xb + r * LL + base);
  };

  auto process = [&](int sc, const float4* buf) {
    const int base = sc * 256 + lane * 4;
    const float4 x4 = buf[0];
    const float4 B4 = buf[1];
    const float4 C4 = buf[2];
    float xx[4] = {x4.x, x4.y, x4.z, x4.w};
    float bb[4] = {B4.x, B4.y, B4.z, B4.w};
    float av[4], bv[4];
    float aggA = 1.f, aggB = 0.f;
#pragma unroll
    for (int q = 0; q < 4; ++q) {
      float z = db;
#pragma unroll
      for (int r = 0; r < DTR; ++r) z += dw[r] * ((&buf[3 + r].x)[q]);
      float delta = (z > 15.f) ? z : __logf(1.f + __expf(z));
      float a = __expf(delta * Ac);
      float be = delta * bb[q] * xx[q];
      av[q] = a;
      bv[q] = be;
      aggA = a * aggA;
      aggB = a * aggB + be;
    }

    float incA = aggA, incB = aggB;
#pragma unroll
    for (int s = 1; s < 64; s <<= 1) {
      float pA = __shfl_up(incA, (unsigned)s, 64);
      float pB = __shfl_up(incB, (unsigned)s, 64);
      if (lane >= s) {
        incB = incA * pB + incB;
        incA = incA * pA;
      }
    }
    float eA = __shfl_up(incA, 1u, 64);
    float eB = __shfl_up(incB, 1u, 64);
    if (lane == 0) { eA = 1.f; eB = 0.f; }
    float tA = __shfl(incA, 63, 64);
    float tB = __shfl(incB, 63, 64);

    float h = eA * hcarry + eB;
    float ov[4];
#pragma unroll
    for (int q = 0; q < 4; ++q) {
      h = av[q] * h + bv[q];
      ov[q] = h * ((&C4.x)[q]) + xx[q] * Dc;
    }
    float4 o;
    o.x = ov[0]; o.y = ov[1]; o.z = ov[2]; o.w = ov[3];
    *(float4*)(yp + base) = o;

    hcarry = tA * hcarry + tB;
  };

  float4 bufA[15], bufB[15];
  load_chunk(0, bufA);
  for (int i = 0; i < 8; ++i) {
    const int s0 = 2 * i;
    load_chunk(s0 + 1, bufB);
    process(s0, bufA);
    load_chunk(s0 + 2 < 16 ? s0 + 2 : 15, bufA);  // clamped (redundant at end)
    process(s0 + 1, bufB);
  }
}

// ---------------------------------------------------------------------------
extern "C" void kernel_launch(void* const* d_in, const int* in_sizes, int n_in,
                              void* d_out, int out_size, void* d_ws,
                              size_t ws_size, hipStream_t stream) {
  const float* x        = (const float*)d_in[0];
  const float* conv_w   = (const float*)d_in[1];
  const float* conv_b   = (const float*)d_in[2];
  const float* x_proj_w = (const float*)d_in[3];
  const float* dt_w     = (const float*)d_in[4];
  const float* dt_b     = (const float*)d_in[5];
  const float* A_logs   = (const float*)d_in[6];
  const float* Ds       = (const float*)d_in[7];
  float* out = (float*)d_out;

  char* ws = (char*)d_ws;
  const size_t plane_bytes = (size_t)BB * CC * LL * sizeof(float);  // 50 MB
  float* xs   = (float*)ws;
  float* xdbl = (float*)(ws + plane_bytes);  // BB*KK*LL floats = 3.67 MB

  conv_silu_kernel<<<dim3(BB * CC), 256, 0, stream>>>(x, conv_w, conv_b, xs);
  proj_kernel<<<dim3(LL / 128, BB), 512, 0, stream>>>(xs, x_proj_w, xdbl);
  scan_kernel<<<dim3(BB * CC), 64, 0, stream>>>(xs, xdbl, dt_w, dt_b,
                                                A_logs, Ds, out);
}